// Round 1
// baseline (796.971 us; speedup 1.0000x reference)
//
#include <hip/hip_runtime.h>
#include <stdint.h>

// Problem: K=6, B=128, N=65536, D=256, fp32 in/out.
// d_out = [soft_labels (K*B*N)] ++ [sim (K*B*N)] fp32.
// d_ws usage: A_hi (393216 B) + A_lo (393216 B) + cand (15728640 B) ~= 16.5 MB.

#define KP 6
#define BROWS 128
#define NCOLS 65536
#define DDIM 256
#define BN 128
#define BK 64
#define NBLK (NCOLS / BN)   // 512
#define T1 512

typedef short bf16x8 __attribute__((ext_vector_type(8)));
typedef float f32x4 __attribute__((ext_vector_type(4)));

__device__ __forceinline__ uint32_t f2bf(float f) {            // fp32 -> bf16 RNE (no NaN in data)
  uint32_t u = __float_as_uint(f);
  return (u + 0x7FFFu + ((u >> 16) & 1u)) >> 16;
}
__device__ __forceinline__ float bf2f(uint32_t h) { return __uint_as_float(h << 16); }

// monotonic key: larger value => larger key; ties (impossible w/ continuous data)
// break toward LOWER index (matches jax.lax.top_k), via ~idx in low bits.
__device__ __forceinline__ unsigned long long mkkey(float v, uint32_t idx) {
  uint32_t u = __float_as_uint(v);
  uint32_t ov = ((int32_t)u < 0) ? ~u : (u | 0x80000000u);
  return ((unsigned long long)ov << 32) | (uint32_t)(~idx);
}
__device__ __forceinline__ float keyval(unsigned long long k) {
  uint32_t ov = (uint32_t)(k >> 32);
  uint32_t u = (ov & 0x80000000u) ? (ov ^ 0x80000000u) : ~ov;
  return __uint_as_float(u);
}
__device__ __forceinline__ uint32_t keyidx(unsigned long long k) { return ~(uint32_t)k; }

// insert into descending sorted 5-list
__device__ __forceinline__ void ins5(unsigned long long* t, unsigned long long key) {
  if (key > t[4]) {
    t[4] = key;
#pragma unroll
    for (int q = 4; q > 0; --q)
      if (t[q] > t[q - 1]) { unsigned long long tmp = t[q]; t[q] = t[q - 1]; t[q - 1] = tmp; }
  }
}

// XOR-swizzled LDS offset for [128][BK] bf16 row-major tiles (T2: breaks the
// 16-way conflict of 128 B row stride on ds_read_b128; preserves 8B/16B align).
__device__ __forceinline__ int ldsOff(int row, int colByte) {
  return ((row << 7) + colByte) ^ ((row & 7) << 4);
}

// ---------------- kernel 0: L2-normalize rows of part_features, split fp32 -> bf16 hi/lo
__global__ __launch_bounds__(256) void norm_split(const float* __restrict__ part,
                                                  uint16_t* __restrict__ ahi,
                                                  uint16_t* __restrict__ alo) {
  int row = blockIdx.x;             // k*128 + b
  int t = threadIdx.x;              // = d (DDIM == 256)
  float x = part[(size_t)row * DDIM + t];
  float ss = x * x;
#pragma unroll
  for (int off = 32; off; off >>= 1) ss += __shfl_down(ss, off, 64);
  __shared__ float wsum[4];
  __shared__ float nrm;
  if ((t & 63) == 0) wsum[t >> 6] = ss;
  __syncthreads();
  if (t == 0) nrm = fmaxf(sqrtf(wsum[0] + wsum[1] + wsum[2] + wsum[3]), 1e-12f);
  __syncthreads();
  float xf = x / nrm;
  uint32_t h = f2bf(xf);
  uint32_t l = f2bf(xf - bf2f(h));
  ahi[(size_t)row * DDIM + t] = (uint16_t)h;
  alo[(size_t)row * DDIM + t] = (uint16_t)l;
}

// ---------------- kernel 1: split-bf16 MFMA GEMM tile (128 x 128) + sim write +
// soft zeros + in-register per-tile top-5 -> candidate buffer
__global__ __launch_bounds__(T1) void gemm_topk(const float* __restrict__ memB,
                                                const uint16_t* __restrict__ ahi,
                                                const uint16_t* __restrict__ alo,
                                                float* __restrict__ soft,
                                                float* __restrict__ sim,
                                                unsigned long long* __restrict__ cand) {
  __shared__ __align__(16) char smem[65536];
  char* AH = smem;            // [128][64] bf16 hi   (16 KB)
  char* AL = smem + 16384;    // [128][64] bf16 lo
  char* BH = smem + 32768;
  char* BL = smem + 49152;

  const int k = blockIdx.y;
  const int nb = blockIdx.x;
  const int n0 = nb * BN;
  const int tid = threadIdx.x;
  const int lane = tid & 63;
  const int wv = tid >> 6;        // 0..7
  const int wm = wv >> 2;         // 0..1  (64 rows each)
  const int wn = wv & 3;          // 0..3  (32 cols each)
  const int l15 = lane & 15;
  const int lq = lane >> 4;       // 0..3

  const float* Bbase = memB + ((size_t)k * NCOLS + n0) * DDIM;
  const uint16_t* AHg = ahi + (size_t)k * BROWS * DDIM;
  const uint16_t* ALg = alo + (size_t)k * BROWS * DDIM;

  f32x4 acc[4][2];
#pragma unroll
  for (int mf = 0; mf < 4; ++mf)
#pragma unroll
    for (int nf = 0; nf < 2; ++nf) acc[mf][nf] = (f32x4)(0.0f);

  float4 rb[4];           // B chunk staging (128x64 fp32 / 512 thr = 4 float4)
  uint4 rah[2], ral[2];   // A chunk staging (128x64 bf16 / 512 thr = 2x16B each)

  auto loadChunk = [&](int c) {
#pragma unroll
    for (int p = 0; p < 4; ++p) {
      int e = (p * T1 + tid) * 4;      // element in 128x64 tile
      int r = e >> 6, cl = e & 63;
      rb[p] = *(const float4*)(Bbase + (size_t)r * DDIM + c * BK + cl);
    }
#pragma unroll
    for (int p = 0; p < 2; ++p) {
      int e = (p * T1 + tid) * 8;
      int r = e >> 6, cl = e & 63;
      rah[p] = *(const uint4*)(AHg + (size_t)r * DDIM + c * BK + cl);
      ral[p] = *(const uint4*)(ALg + (size_t)r * DDIM + c * BK + cl);
    }
  };

  auto storeStage = [&]() {
#pragma unroll
    for (int p = 0; p < 4; ++p) {
      int e = (p * T1 + tid) * 4;
      int r = e >> 6, cl = e & 63;
      uint32_t h0 = f2bf(rb[p].x), h1 = f2bf(rb[p].y), h2 = f2bf(rb[p].z), h3 = f2bf(rb[p].w);
      uint32_t l0 = f2bf(rb[p].x - bf2f(h0));
      uint32_t l1 = f2bf(rb[p].y - bf2f(h1));
      uint32_t l2 = f2bf(rb[p].z - bf2f(h2));
      uint32_t l3 = f2bf(rb[p].w - bf2f(h3));
      int off = ldsOff(r, cl * 2);
      *(uint2*)(BH + off) = make_uint2(h0 | (h1 << 16), h2 | (h3 << 16));
      *(uint2*)(BL + off) = make_uint2(l0 | (l1 << 16), l2 | (l3 << 16));
    }
#pragma unroll
    for (int p = 0; p < 2; ++p) {
      int e = (p * T1 + tid) * 8;
      int r = e >> 6, cl = e & 63;
      int off = ldsOff(r, cl * 2);
      *(uint4*)(AH + off) = rah[p];
      *(uint4*)(AL + off) = ral[p];
    }
  };

  loadChunk(0);
#pragma unroll
  for (int c = 0; c < 4; ++c) {
    if (c) __syncthreads();              // previous chunk's readers done
    storeStage();
    __syncthreads();
    if (c < 3) loadChunk(c + 1);         // prefetch next chunk under compute (T14-lite)
#pragma unroll
    for (int kk = 0; kk < BK; kk += 32) {
      bf16x8 afh[4], afl[4], bfh[2], bfl[2];
      int cb = (kk + 8 * lq) * 2;
#pragma unroll
      for (int mf = 0; mf < 4; ++mf) {
        int r = wm * 64 + mf * 16 + l15;
        afh[mf] = *(const bf16x8*)(AH + ldsOff(r, cb));
        afl[mf] = *(const bf16x8*)(AL + ldsOff(r, cb));
      }
#pragma unroll
      for (int nf = 0; nf < 2; ++nf) {
        int r = wn * 32 + nf * 16 + l15;
        bfh[nf] = *(const bf16x8*)(BH + ldsOff(r, cb));
        bfl[nf] = *(const bf16x8*)(BL + ldsOff(r, cb));
      }
#pragma unroll
      for (int mf = 0; mf < 4; ++mf)
#pragma unroll
        for (int nf = 0; nf < 2; ++nf) {
          acc[mf][nf] = __builtin_amdgcn_mfma_f32_16x16x32_bf16(afh[mf], bfh[nf], acc[mf][nf], 0, 0, 0);
          acc[mf][nf] = __builtin_amdgcn_mfma_f32_16x16x32_bf16(afh[mf], bfl[nf], acc[mf][nf], 0, 0, 0);
          acc[mf][nf] = __builtin_amdgcn_mfma_f32_16x16x32_bf16(afl[mf], bfh[nf], acc[mf][nf], 0, 0, 0);
        }
    }
  }

  // ---- epilogue: sim stores (from C frags: col=lane&15, row=(lane>>4)*4+reg) ----
#pragma unroll
  for (int mf = 0; mf < 4; ++mf)
#pragma unroll
    for (int nf = 0; nf < 2; ++nf)
#pragma unroll
      for (int j = 0; j < 4; ++j) {
        int row = wm * 64 + mf * 16 + lq * 4 + j;
        int ccol = wn * 32 + nf * 16 + l15;
        sim[(size_t)(k * BROWS + row) * NCOLS + n0 + ccol] = acc[mf][nf][j];
      }
  // zeros for soft_labels tile (coalesced float4)
  {
    const size_t softbase = (size_t)(k * BROWS) * NCOLS + n0;
    float4 z4 = make_float4(0.f, 0.f, 0.f, 0.f);
#pragma unroll
    for (int p = 0; p < 8; ++p) {
      int e = (p * T1 + tid) * 4;     // 128*128 floats
      int r = e >> 7, ccol = e & 127;
      *(float4*)(soft + softbase + (size_t)r * NCOLS + ccol) = z4;
    }
  }

  // ---- in-register per-row top-5 over this tile's 32 cols per wave ----
  __syncthreads();                            // staging LDS now dead -> reuse for CAND
  unsigned long long* CAND = (unsigned long long*)smem;  // [128 rows][4 wn][5]
#pragma unroll
  for (int mf = 0; mf < 4; ++mf) {
#pragma unroll
    for (int j = 0; j < 4; ++j) {
      int row = wm * 64 + mf * 16 + lq * 4 + j;
      unsigned long long k0 = mkkey(acc[mf][0][j], (uint32_t)(n0 + wn * 32 + l15));
      unsigned long long k1 = mkkey(acc[mf][1][j], (uint32_t)(n0 + wn * 32 + 16 + l15));
      unsigned long long w0, w1, w2, w3, w4;
#pragma unroll
      for (int rd = 0; rd < 5; ++rd) {
        unsigned long long km = k0 > k1 ? k0 : k1;
#pragma unroll
        for (int s = 1; s < 16; s <<= 1) {     // reduce within 16-lane row-group
          unsigned long long o = __shfl_xor(km, s, 64);
          if (o > km) km = o;
        }
        if (rd == 0) w0 = km; else if (rd == 1) w1 = km; else if (rd == 2) w2 = km;
        else if (rd == 3) w3 = km; else w4 = km;
        if (k0 == km) k0 = 0; else if (k1 == km) k1 = 0;   // remove winner (keys unique)
      }
      if (l15 == 0) {
        unsigned long long* dst = &CAND[(row * 4 + wn) * 5];
        dst[0] = w0; dst[1] = w1; dst[2] = w2; dst[3] = w3; dst[4] = w4;
      }
    }
  }
  __syncthreads();
  if (tid < BROWS) {   // merge the 4 wn-lists per row, emit per-tile candidates
    unsigned long long m[5] = {0, 0, 0, 0, 0};
#pragma unroll
    for (int g = 0; g < 4; ++g)
#pragma unroll
      for (int j = 0; j < 5; ++j) ins5(m, CAND[(tid * 4 + g) * 5 + j]);
    size_t cb = ((size_t)(k * BROWS + tid) * NBLK + nb) * 5;
#pragma unroll
    for (int j = 0; j < 5; ++j) cand[cb + j] = m[j];
  }
}

// ---------------- kernel 2: reduce candidates per row -> top-5 softmax -> scatter
__global__ __launch_bounds__(256) void topk_softmax(const unsigned long long* __restrict__ cand,
                                                    float* __restrict__ soft) {
  int row = blockIdx.x;   // k*128 + b
  const unsigned long long* cb = cand + (size_t)row * NBLK * 5;
  unsigned long long t5[5] = {0, 0, 0, 0, 0};
  for (int i = threadIdx.x; i < NBLK * 5; i += 256) ins5(t5, cb[i]);
  __shared__ unsigned long long lds[256 * 5];
#pragma unroll
  for (int j = 0; j < 5; ++j) lds[threadIdx.x * 5 + j] = t5[j];
  __syncthreads();
  if (threadIdx.x < 64) {
    unsigned long long m[5] = {0, 0, 0, 0, 0};
#pragma unroll
    for (int g = 0; g < 4; ++g)
#pragma unroll
      for (int j = 0; j < 5; ++j) ins5(m, lds[(threadIdx.x * 4 + g) * 5 + j]);
#pragma unroll
    for (int off = 1; off < 64; off <<= 1) {   // butterfly merge of sorted 5-lists
      unsigned long long o[5];
#pragma unroll
      for (int j = 0; j < 5; ++j) o[j] = __shfl_xor(m[j], off, 64);
      unsigned long long out[5];
      int a = 0, b2 = 0;
#pragma unroll
      for (int r = 0; r < 5; ++r) out[r] = (m[a] >= o[b2]) ? m[a++] : o[b2++];
#pragma unroll
      for (int j = 0; j < 5; ++j) m[j] = out[j];
    }
    if (threadIdx.x == 0) {
      float v[5]; uint32_t ix[5];
#pragma unroll
      for (int j = 0; j < 5; ++j) { v[j] = keyval(m[j]); ix[j] = keyidx(m[j]); }
      float mx = v[0];     // m[0] is the max
      float e[5], Z = 0.f;
#pragma unroll
      for (int j = 0; j < 5; ++j) { e[j] = expf((v[j] - mx) * (1.0f / 3.0f)); Z += e[j]; }
      float invZ = 1.0f / Z;
#pragma unroll
      for (int j = 0; j < 5; ++j) soft[(size_t)row * NCOLS + ix[j]] = e[j] * invZ;
    }
  }
}

extern "C" void kernel_launch(void* const* d_in, const int* in_sizes, int n_in,
                              void* d_out, int out_size, void* d_ws, size_t ws_size,
                              hipStream_t stream) {
  const float* part = (const float*)d_in[0];    // [6,128,256]
  const float* memB = (const float*)d_in[1];    // [6,65536,256]
  float* soft = (float*)d_out;                                  // [6,128,65536]
  float* sim = soft + (size_t)KP * BROWS * NCOLS;               // [6,128,65536]

  uint16_t* ahi = (uint16_t*)d_ws;
  uint16_t* alo = ahi + (size_t)KP * BROWS * DDIM;
  unsigned long long* cand =
      (unsigned long long*)((char*)d_ws + (size_t)2 * KP * BROWS * DDIM * sizeof(uint16_t));

  norm_split<<<KP * BROWS, 256, 0, stream>>>(part, ahi, alo);
  dim3 g1(NBLK, KP);
  gemm_topk<<<g1, T1, 0, stream>>>(memB, ahi, alo, soft, sim, cand);
  topk_softmax<<<KP * BROWS, 256, 0, stream>>>(cand, soft);
}